// Round 3
// baseline (715.785 us; speedup 1.0000x reference)
//
#include <hip/hip_runtime.h>

#define NELEM 8388608    // 8*256*64*64
#define M_GAP 8e-5f

typedef short s16x8 __attribute__((ext_vector_type(8)));
typedef float f32x4 __attribute__((ext_vector_type(4)));

__device__ __forceinline__ unsigned short bf16r(float f) {
  unsigned u = __float_as_uint(f);
  return (unsigned short)((u + 0x7fffu + ((u >> 16) & 1u)) >> 16);
}
__device__ __forceinline__ float bf16f(unsigned short h) {
  return __uint_as_float(((unsigned)h) << 16);
}

// numpy pairwise sum of squares, 128-block: 8 accumulators stride 8,
// combined ((r0+r1)+(r2+r3))+((r4+r5)+(r6+r7)). All single-rounded f32.
__device__ __forceinline__ float pw128_sq(const float* p, int s) {
  float r[8];
#pragma unroll
  for (int j = 0; j < 8; ++j) { float v = p[j * s]; r[j] = __fmul_rn(v, v); }
#pragma unroll
  for (int i = 8; i < 128; i += 8) {
#pragma unroll
    for (int j = 0; j < 8; ++j) {
      float v = p[(i + j) * s];
      r[j] = __fadd_rn(r[j], __fmul_rn(v, v));
    }
  }
  return __fadd_rn(__fadd_rn(__fadd_rn(r[0], r[1]), __fadd_rn(r[2], r[3])),
                   __fadd_rn(__fadd_rn(r[4], r[5]), __fadd_rn(r[6], r[7])));
}
__device__ __forceinline__ float np_sumsq256(const float* p, int s) {
  return __fadd_rn(pw128_sq(p, s), pw128_sq(p + 128 * s, s));
}

// ---------------- prep: codebook bf16 split + np-exact norms ----------------
__global__ __launch_bounds__(256)
void vq_prep(const float* __restrict__ cb, unsigned short* __restrict__ cbh,
             unsigned short* __restrict__ cbl, float* __restrict__ Bsg) {
  int j = blockIdx.x * 256 + threadIdx.x;   // 0..1023
  const float* r0 = cb + (size_t)j * 256;
  Bsg[j] = np_sumsq256(r0, 1);
  const float4* r4 = reinterpret_cast<const float4*>(r0);
  for (int c4 = 0; c4 < 64; ++c4) {
    float4 v = r4[c4];
    float vv[4] = {v.x, v.y, v.z, v.w};
    ushort4 h4, l4;
    unsigned short* hp = &h4.x;
    unsigned short* lp = &l4.x;
#pragma unroll
    for (int q = 0; q < 4; ++q) {
      unsigned short h = bf16r(vv[q]);
      hp[q] = h;
      lp[q] = bf16r(vv[q] - bf16f(h));
    }
    *reinterpret_cast<ushort4*>(cbh + (size_t)j * 256 + c4 * 4) = h4;
    *reinterpret_cast<ushort4*>(cbl + (size_t)j * 256 + c4 * 4) = l4;
  }
}

// ---------------- phase 1: MFMA scoring + top-2 + ambiguity flag ------------
__global__ __launch_bounds__(512)
void vq_fast(const float* __restrict__ z,
             const unsigned short* __restrict__ cbh,
             const unsigned short* __restrict__ cbl,
             const float* __restrict__ Bsg,
             unsigned* __restrict__ idxw, unsigned* __restrict__ list,
             unsigned* __restrict__ cnt) {
  __shared__ __align__(16) unsigned short Ah[128 * 256];   // 64 KB
  __shared__ __align__(16) unsigned short Al[128 * 256];   // 64 KB
  __shared__ float BsL[1024];                              // 4 KB
  const int t = threadIdx.x;
  const int bid = blockIdx.x;          // 0..255, rows n0 = bid*128
  const int lane = t & 63;
  const int wv = t >> 6;               // wave 0..7, rows wv*16..wv*16+15
  const int l15 = lane & 15;
  const int lk = lane >> 4;            // 0..3

  // stage z rows -> bf16 hi/lo, transposed [row][c] with XOR swizzle
#pragma unroll
  for (int i = 0; i < 16; ++i) {
    int idx4 = t + i * 512;            // 0..8191
    int p = idx4 >> 12;                // which (b,h) pair
    int rem = idx4 & 4095;
    int c = rem >> 4;
    int w4 = rem & 15;
    int bh = bid * 2 + p;
    const float4* src = reinterpret_cast<const float4*>(
        z + (size_t)(bh >> 6) * (256 * 4096) + (size_t)(bh & 63) * 64 +
        (size_t)c * 4096) + w4;
    float4 v = *src;
    float vv[4] = {v.x, v.y, v.z, v.w};
#pragma unroll
    for (int q = 0; q < 4; ++q) {
      int row = p * 64 + w4 * 4 + q;
      int e = row * 256 + (c ^ ((row & 31) << 3));
      unsigned short h = bf16r(vv[q]);
      Ah[e] = h;
      Al[e] = bf16r(vv[q] - bf16f(h));
    }
  }
  for (int i = t; i < 1024; i += 512) BsL[i] = Bsg[i];
  __syncthreads();

  // preload a-frags (rows = wv*16 + l15, k = kk*32 + lk*8 .. +7)
  const int row = wv * 16 + l15;
  const int sw = (row & 31) << 3;
  s16x8 ah[8], al[8];
#pragma unroll
  for (int kk = 0; kk < 8; ++kk) {
    int e = row * 256 + ((kk * 32 + lk * 8) ^ sw);
    ah[kk] = *reinterpret_cast<const s16x8*>(&Ah[e]);
    al[kk] = *reinterpret_cast<const s16x8*>(&Al[e]);
  }

  float b1v[4], b2v[4];
  int b1i[4];
#pragma unroll
  for (int r = 0; r < 4; ++r) { b1v[r] = 3.4e38f; b2v[r] = 3.4e38f; b1i[r] = 0; }

  for (int jt = 0; jt < 16; ++jt) {
    f32x4 acc[4];
#pragma unroll
    for (int js = 0; js < 4; ++js) acc[js] = (f32x4){0.f, 0.f, 0.f, 0.f};
    const size_t bbase = (size_t)(jt * 64 + l15) * 256 + lk * 8;
    const unsigned short* bph = cbh + bbase;
    const unsigned short* bpl = cbl + bbase;
#pragma unroll 2
    for (int kk = 0; kk < 8; ++kk) {
#pragma unroll
      for (int js = 0; js < 4; ++js) {
        int off = js * 16 * 256 + kk * 32;
        s16x8 bh = *reinterpret_cast<const s16x8*>(bph + off);
        s16x8 bl = *reinterpret_cast<const s16x8*>(bpl + off);
        acc[js] = __builtin_amdgcn_mfma_f32_16x16x32_bf16(al[kk], bh, acc[js], 0, 0, 0);
        acc[js] = __builtin_amdgcn_mfma_f32_16x16x32_bf16(ah[kk], bl, acc[js], 0, 0, 0);
        acc[js] = __builtin_amdgcn_mfma_f32_16x16x32_bf16(ah[kk], bh, acc[js], 0, 0, 0);
      }
    }
#pragma unroll
    for (int js = 0; js < 4; ++js) {
      int j = jt * 64 + js * 16 + l15;     // this lane's column
      float Bj = BsL[j];
#pragma unroll
      for (int r = 0; r < 4; ++r) {
        float s = fmaf(-2.0f, acc[js][r], Bj);
        bool lt = s < b1v[r];
        float other = lt ? b1v[r] : s;
        b2v[r] = fminf(b2v[r], other);
        b1v[r] = fminf(b1v[r], s);
        b1i[r] = lt ? j : b1i[r];
      }
    }
  }

  // merge top-2 across the 16 lanes sharing rows (lanes with same lane>>4)
#pragma unroll
  for (int mk = 1; mk < 16; mk <<= 1) {
#pragma unroll
    for (int r = 0; r < 4; ++r) {
      float ov1 = __shfl_xor(b1v[r], mk, 64);
      float ov2 = __shfl_xor(b2v[r], mk, 64);
      int oi1 = __shfl_xor(b1i[r], mk, 64);
      bool lt = ov1 < b1v[r];
      float hi = lt ? b1v[r] : ov1;
      b2v[r] = fminf(fminf(b2v[r], ov2), hi);
      b1v[r] = fminf(b1v[r], ov1);
      b1i[r] = lt ? oi1 : b1i[r];
    }
  }
  if (l15 == 0) {
#pragma unroll
    for (int r = 0; r < 4; ++r) {
      int n = bid * 128 + wv * 16 + lk * 4 + r;   // D row = (lane>>4)*4 + reg
      idxw[n] = (unsigned)b1i[r];
      if (b2v[r] - b1v[r] <= M_GAP) {
        unsigned pos = atomicAdd(cnt, 1u);
        list[pos] = (unsigned)n;
      }
    }
  }
}

// ---------------- phase 2: exact np-chain rescore of flagged rows -----------
__global__ __launch_bounds__(256)
void vq_exact(const float* __restrict__ z, const float* __restrict__ cb,
              const float* __restrict__ Bsg, const unsigned* __restrict__ list,
              const unsigned* __restrict__ cnt, unsigned* __restrict__ idxw) {
  __shared__ float zrow[256];
  __shared__ float Ash;
  __shared__ float rv[256];
  __shared__ int ri[256];
  const int t = threadIdx.x;
  const unsigned K = *cnt;
  for (unsigned it = blockIdx.x; it < K; it += gridDim.x) {
    int n = (int)list[it];
    int b = n >> 12;
    int hw = n & 4095;
    __syncthreads();   // protect zrow/rv reuse across iterations
    zrow[t] = z[(size_t)b * (256 * 4096) + (size_t)t * 4096 + hw];
    __syncthreads();
    if (t == 0) Ash = np_sumsq256(zrow, 1);
    __syncthreads();
    const float A = Ash;
    // 4 sequential-fmaf chains (c ascending = OpenBLAS order), j = 4t..4t+3
    float acc[4] = {0.f, 0.f, 0.f, 0.f};
    const float* cbb = cb + (size_t)t * 4 * 256;
    const float4* z4 = reinterpret_cast<const float4*>(zrow);
    for (int c4 = 0; c4 < 64; ++c4) {
      float4 zv = z4[c4];
      float zz[4] = {zv.x, zv.y, zv.z, zv.w};
#pragma unroll
      for (int q = 0; q < 4; ++q) {
        float4 cv = reinterpret_cast<const float4*>(cbb + q * 256)[c4];
        acc[q] = fmaf(zz[0], cv.x, acc[q]);
        acc[q] = fmaf(zz[1], cv.y, acc[q]);
        acc[q] = fmaf(zz[2], cv.z, acc[q]);
        acc[q] = fmaf(zz[3], cv.w, acc[q]);
      }
    }
    float bv = 3.4e38f;
    int bi = 0;
#pragma unroll
    for (int q = 0; q < 4; ++q) {
      int j = t * 4 + q;
      float dd = __fsub_rn(__fadd_rn(A, Bsg[j]), __fmul_rn(2.0f, acc[q]));
      if (dd < bv) { bv = dd; bi = j; }
    }
    rv[t] = bv; ri[t] = bi;
    __syncthreads();
    for (int s2 = 128; s2 > 0; s2 >>= 1) {
      if (t < s2) {
        float v2 = rv[t + s2]; int i2 = ri[t + s2];
        if (v2 < rv[t] || (v2 == rv[t] && i2 < ri[t])) { rv[t] = v2; ri[t] = i2; }
      }
      __syncthreads();
    }
    if (t == 0) idxw[n] = (unsigned)ri[0];
  }
}

// ---------------- phase 3: gather z_q, write idx, loss ----------------------
__global__ __launch_bounds__(256)
void vq_out(const float* __restrict__ z, const float* __restrict__ cb,
            const unsigned* __restrict__ idxw, float* __restrict__ zq,
            float* __restrict__ loss, float* __restrict__ idxo) {
  __shared__ int bj[64];
  __shared__ double wred[4];
  const int t = threadIdx.x;
  const int bid = blockIdx.x;          // (b,h)
  const int n0 = bid * 64;
  if (t < 64) {
    int j = (int)idxw[n0 + t];
    bj[t] = j;
    idxo[n0 + t] = (float)j;
  }
  __syncthreads();
  const float* zb = z + (size_t)(bid >> 6) * (256 * 4096) + (size_t)(bid & 63) * 64;
  float* zqb = zq + (size_t)(bid >> 6) * (256 * 4096) + (size_t)(bid & 63) * 64;
  double ls = 0.0;
  for (int i = 0; i < 64; ++i) {
    int e = t + i * 256;
    int c = e >> 6, w = e & 63;
    float zv = zb[(size_t)c * 4096 + w];
    float cv = cb[(size_t)bj[w] * 256 + c];
    zqb[(size_t)c * 4096 + w] = cv;
    double d = (double)cv - (double)zv;
    ls += d * d;
  }
#pragma unroll
  for (int off = 32; off > 0; off >>= 1) ls += __shfl_down(ls, off, 64);
  if ((t & 63) == 0) wred[t >> 6] = ls;
  __syncthreads();
  if (t == 0) {
    double tot = wred[0] + wred[1] + wred[2] + wred[3];
    atomicAdd(loss, (float)(tot * (1.25 / (double)NELEM)));
  }
}

// ---------------- fallback (round-2 validated all-exact kernel) -------------
__global__ __launch_bounds__(256)
void vq_ref(const float* __restrict__ z, const float* __restrict__ cb,
            float* __restrict__ zq, float* __restrict__ loss,
            float* __restrict__ idxo) {
  __shared__ __align__(16) float zt[256 * 64];
  __shared__ __align__(16) float cbt[256 * 64];
  __shared__ float As[64];
  __shared__ float Bs[64];
  __shared__ int bestj[64];
  __shared__ float cand_v[16 * 64];
  __shared__ int cand_i[16 * 64];
  __shared__ double wred[4];
  const int t = threadIdx.x;
  const int wg = t & 15, jg = t >> 4;
  const int bid = blockIdx.x;
  const int b = bid >> 6, h = bid & 63;
  const int n0 = bid * 64;
  const float4* z4 = reinterpret_cast<const float4*>(z + (size_t)b * 256 * 4096 + (size_t)h * 64);
  float4* zt4 = reinterpret_cast<float4*>(zt);
#pragma unroll
  for (int i = 0; i < 16; ++i) {
    int idx4 = t + i * 256;
    zt4[idx4] = z4[(size_t)(idx4 >> 4) * 1024 + (idx4 & 15)];
  }
  __syncthreads();
  if (t < 64) As[t] = np_sumsq256(zt + t, 64);
  float bv[4]; int bi[4];
#pragma unroll
  for (int a = 0; a < 4; ++a) { bv[a] = 3.4e38f; bi[a] = 0; }
  for (int p = 0; p < 16; ++p) {
    __syncthreads();
    const float4* cb4 = reinterpret_cast<const float4*>(cb) + (size_t)p * 64 * 64;
#pragma unroll
    for (int i = 0; i < 16; ++i) {
      int idx4 = t + i * 256;
      int jj = idx4 >> 6, c4 = idx4 & 63;
      float4 v = cb4[idx4];
      cbt[(c4 * 4 + 0) * 64 + jj] = v.x;
      cbt[(c4 * 4 + 1) * 64 + jj] = v.y;
      cbt[(c4 * 4 + 2) * 64 + jj] = v.z;
      cbt[(c4 * 4 + 3) * 64 + jj] = v.w;
    }
    __syncthreads();
    if (t < 64) Bs[t] = np_sumsq256(cbt + t, 64);
    float acc[4][4];
#pragma unroll
    for (int a = 0; a < 4; ++a)
#pragma unroll
      for (int u = 0; u < 4; ++u) acc[a][u] = 0.0f;
    const float4* ztp = reinterpret_cast<const float4*>(zt) + wg;
    const float4* cbp = reinterpret_cast<const float4*>(cbt) + jg;
#pragma unroll 4
    for (int c = 0; c < 256; ++c) {
      float4 zv = ztp[c * 16];
      float4 cv = cbp[c * 16];
      float za[4] = {zv.x, zv.y, zv.z, zv.w};
      float ca[4] = {cv.x, cv.y, cv.z, cv.w};
#pragma unroll
      for (int a = 0; a < 4; ++a)
#pragma unroll
        for (int u = 0; u < 4; ++u) acc[a][u] = fmaf(za[a], ca[u], acc[a][u]);
    }
    __syncthreads();
#pragma unroll
    for (int u = 0; u < 4; ++u) {
      int j = p * 64 + jg * 4 + u;
      float Bju = Bs[jg * 4 + u];
#pragma unroll
      for (int a = 0; a < 4; ++a) {
        float AB = __fadd_rn(As[wg * 4 + a], Bju);
        float dd = __fsub_rn(AB, __fmul_rn(2.0f, acc[a][u]));
        if (dd < bv[a]) { bv[a] = dd; bi[a] = j; }
      }
    }
  }
  __syncthreads();
#pragma unroll
  for (int a = 0; a < 4; ++a) {
    int w = wg * 4 + a;
    cand_v[jg * 64 + w] = bv[a];
    cand_i[jg * 64 + w] = bi[a];
  }
  __syncthreads();
  if (t < 64) {
    float v0 = cand_v[t]; int i0 = cand_i[t];
    for (int g = 1; g < 16; ++g) {
      float v = cand_v[g * 64 + t]; int ii = cand_i[g * 64 + t];
      if (v < v0 || (v == v0 && ii < i0)) { v0 = v; i0 = ii; }
    }
    bestj[t] = i0;
    idxo[n0 + t] = (float)i0;
  }
  __syncthreads();
  double lsum = 0.0;
  float* zqbase = zq + (size_t)b * 256 * 4096 + (size_t)h * 64;
  for (int i = 0; i < 64; ++i) {
    int idx = t + i * 256;
    int c = idx >> 6, w = idx & 63;
    float zvv = zt[c * 64 + w];
    float cvv = cb[(size_t)bestj[w] * 256 + c];
    zqbase[(size_t)c * 4096 + w] = cvv;
    double d = (double)cvv - (double)zvv;
    lsum += d * d;
  }
#pragma unroll
  for (int off = 32; off > 0; off >>= 1) lsum += __shfl_down(lsum, off, 64);
  if ((t & 63) == 0) wred[t >> 6] = lsum;
  __syncthreads();
  if (t == 0) {
    double tot = wred[0] + wred[1] + wred[2] + wred[3];
    atomicAdd(loss, (float)(tot * (1.25 / (double)NELEM)));
  }
}

extern "C" void kernel_launch(void* const* d_in, const int* in_sizes, int n_in,
                              void* d_out, int out_size, void* d_ws, size_t ws_size,
                              hipStream_t stream) {
  (void)in_sizes; (void)n_in; (void)out_size;
  const float* z = (const float*)d_in[0];
  const float* cb = (const float*)d_in[1];
  float* out = (float*)d_out;
  float* zq = out;
  float* loss = out + NELEM;
  float* idxo = out + NELEM + 1;
  hipMemsetAsync(loss, 0, sizeof(float), stream);
  if (ws_size < 1400000) {   // scratch too small: validated all-exact path
    vq_ref<<<512, 256, 0, stream>>>(z, cb, zq, loss, idxo);
    return;
  }
  unsigned* cnt = (unsigned*)d_ws;
  float* Bsg = (float*)d_ws + 64;
  unsigned* idxw = (unsigned*)d_ws + 1088;
  unsigned* list = (unsigned*)d_ws + 33856;
  unsigned short* cbh = (unsigned short*)((float*)d_ws + 66624);
  unsigned short* cbl = cbh + 262144;
  hipMemsetAsync(cnt, 0, sizeof(unsigned), stream);
  vq_prep<<<4, 256, 0, stream>>>(cb, cbh, cbl, Bsg);
  vq_fast<<<256, 512, 0, stream>>>(z, cbh, cbl, Bsg, idxw, list, cnt);
  vq_exact<<<128, 256, 0, stream>>>(z, cb, Bsg, list, cnt, idxw);
  vq_out<<<512, 256, 0, stream>>>(z, cb, idxw, zq, loss, idxo);
}

// Round 4
// 177.276 us; speedup vs baseline: 4.0377x; 4.0377x over previous
//
#include <hip/hip_runtime.h>

#define NELEM 8388608    // 8*256*64*64
#define M_GAP 8e-5f

typedef short s16x8 __attribute__((ext_vector_type(8)));
typedef float f32x4 __attribute__((ext_vector_type(4)));

__device__ __forceinline__ unsigned short bf16r(float f) {
  unsigned u = __float_as_uint(f);
  return (unsigned short)((u + 0x7fffu + ((u >> 16) & 1u)) >> 16);
}
__device__ __forceinline__ float bf16f(unsigned short h) {
  return __uint_as_float(((unsigned)h) << 16);
}

// numpy pairwise sum of squares, 128-block: 8 accumulators stride 8,
// combined ((r0+r1)+(r2+r3))+((r4+r5)+(r6+r7)). All single-rounded f32.
__device__ __forceinline__ float pw128_sq(const float* p, int s) {
  float r[8];
#pragma unroll
  for (int j = 0; j < 8; ++j) { float v = p[j * s]; r[j] = __fmul_rn(v, v); }
#pragma unroll
  for (int i = 8; i < 128; i += 8) {
#pragma unroll
    for (int j = 0; j < 8; ++j) {
      float v = p[(i + j) * s];
      r[j] = __fadd_rn(r[j], __fmul_rn(v, v));
    }
  }
  return __fadd_rn(__fadd_rn(__fadd_rn(r[0], r[1]), __fadd_rn(r[2], r[3])),
                   __fadd_rn(__fadd_rn(r[4], r[5]), __fadd_rn(r[6], r[7])));
}
__device__ __forceinline__ float np_sumsq256(const float* p, int s) {
  return __fadd_rn(pw128_sq(p, s), pw128_sq(p + 128 * s, s));
}

// ---- prep: codebook bf16 split + np-exact norms + zero cnt/loss ----
__global__ __launch_bounds__(256)
void vq_prep(const float* __restrict__ cb, unsigned short* __restrict__ cbh,
             unsigned short* __restrict__ cbl, float* __restrict__ Bsg,
             unsigned* __restrict__ cnt, float* __restrict__ loss) {
  int gid = blockIdx.x * 256 + threadIdx.x;   // 0..4095
  if (gid == 0) { *cnt = 0u; *loss = 0.0f; }
  int code = gid >> 2, qtr = gid & 3;
  const float4* src = reinterpret_cast<const float4*>(cb + (size_t)code * 256 + qtr * 64);
  unsigned short* dh = cbh + (size_t)code * 256 + qtr * 64;
  unsigned short* dl = cbl + (size_t)code * 256 + qtr * 64;
#pragma unroll
  for (int i = 0; i < 16; ++i) {
    float4 v = src[i];
    float vv[4] = {v.x, v.y, v.z, v.w};
    ushort4 h4, l4;
    unsigned short* hp = &h4.x;
    unsigned short* lp = &l4.x;
#pragma unroll
    for (int q = 0; q < 4; ++q) {
      unsigned short h = bf16r(vv[q]);
      hp[q] = h;
      lp[q] = bf16r(vv[q] - bf16f(h));
    }
    *reinterpret_cast<ushort4*>(dh + i * 4) = h4;
    *reinterpret_cast<ushort4*>(dl + i * 4) = l4;
  }
  if (gid < 1024) Bsg[gid] = np_sumsq256(cb + (size_t)gid * 256, 1);
}

// ---- fast: MFMA scoring (LDS-staged, double-buffered B) + fused epilogue ----
__global__ __launch_bounds__(512, 2)
void vq_fast(const float* __restrict__ z, const float* __restrict__ cb,
             const unsigned short* __restrict__ cbh,
             const unsigned short* __restrict__ cbl,
             const float* __restrict__ Bsg,
             float* __restrict__ zq, float* __restrict__ loss,
             float* __restrict__ idxo,
             unsigned* __restrict__ list, unsigned* __restrict__ cnt) {
  // [0,64K): Ah then Bbuf0 (hi 32K + lo 32K); [64K,128K): Al then Bbuf1
  __shared__ __align__(16) unsigned char ldsraw[131072];
  __shared__ float BsL[1024];
  __shared__ int bestj[128];
  __shared__ unsigned char flg[128];
  __shared__ double wred[8];

  const int t = threadIdx.x;
  const int bid = blockIdx.x;          // 0..255, rows n0 = bid*128
  const int lane = t & 63;
  const int wv = t >> 6;               // wave 0..7, rows wv*16..+15
  const int l15 = lane & 15;
  const int lk = lane >> 4;            // 0..3

  unsigned short* Ah = (unsigned short*)ldsraw;             // [128][256]
  unsigned short* Al = (unsigned short*)(ldsraw + 65536);

  // stage z rows -> bf16 hi/lo, transposed [row][c] with XOR swizzle
#pragma unroll
  for (int i = 0; i < 16; ++i) {
    int idx4 = t + i * 512;            // 0..8191
    int p = idx4 >> 12;
    int rem = idx4 & 4095;
    int c = rem >> 4;
    int w4 = rem & 15;
    int bh = bid * 2 + p;
    const float4* src = reinterpret_cast<const float4*>(
        z + (size_t)(bh >> 6) * (256 * 4096) + (size_t)(bh & 63) * 64 +
        (size_t)c * 4096) + w4;
    float4 v = *src;
    float vv[4] = {v.x, v.y, v.z, v.w};
#pragma unroll
    for (int q = 0; q < 4; ++q) {
      int row = p * 64 + w4 * 4 + q;
      int e = row * 256 + (c ^ ((row & 31) << 3));
      unsigned short h = bf16r(vv[q]);
      Ah[e] = h;
      Al[e] = bf16r(vv[q] - bf16f(h));
    }
  }
  for (int i = t; i < 1024; i += 512) BsL[i] = Bsg[i];
  __syncthreads();

  // preload a-frags (rows = wv*16 + l15, k = kk*32 + lk*8 .. +7)
  const int row = wv * 16 + l15;
  const int sw = (row & 31) << 3;
  s16x8 ah[8], al[8];
#pragma unroll
  for (int kk = 0; kk < 8; ++kk) {
    int e = row * 256 + ((kk * 32 + lk * 8) ^ sw);
    ah[kk] = *reinterpret_cast<const s16x8*>(&Ah[e]);
    al[kk] = *reinterpret_cast<const s16x8*>(&Al[e]);
  }
  __syncthreads();   // all waves done reading Ah/Al; LDS now free for B tiles

  // stage tile 0 into buf0
  {
    unsigned short* bh0 = (unsigned short*)ldsraw;
    unsigned short* bl0 = bh0 + 16384;
#pragma unroll
    for (int i = 0; i < 4; ++i) {
      int idx = t + i * 512;           // 0..2047
      s16x8 vh = *reinterpret_cast<const s16x8*>(cbh + (size_t)idx * 8);
      s16x8 vl = *reinterpret_cast<const s16x8*>(cbl + (size_t)idx * 8);
      int jj = idx >> 5, m = idx & 31;
      int e = jj * 256 + ((m * 8) ^ ((jj & 31) << 3));
      *reinterpret_cast<s16x8*>(bh0 + e) = vh;
      *reinterpret_cast<s16x8*>(bl0 + e) = vl;
    }
  }
  __syncthreads();

  float b1v[4], b2v[4];
  int b1i[4];
#pragma unroll
  for (int r = 0; r < 4; ++r) { b1v[r] = 3.4e38f; b2v[r] = 3.4e38f; b1i[r] = 0; }

  for (int jt = 0; jt < 16; ++jt) {
    // issue next-tile global loads early (latency hides under MFMA)
    s16x8 sh[4], sl[4];
    if (jt < 15) {
      const unsigned short* gh = cbh + (size_t)(jt + 1) * 64 * 256;
      const unsigned short* gl = cbl + (size_t)(jt + 1) * 64 * 256;
#pragma unroll
      for (int i = 0; i < 4; ++i) {
        int idx = t + i * 512;
        sh[i] = *reinterpret_cast<const s16x8*>(gh + (size_t)idx * 8);
        sl[i] = *reinterpret_cast<const s16x8*>(gl + (size_t)idx * 8);
      }
    }

    const unsigned short* bufH = (const unsigned short*)(ldsraw + (jt & 1) * 65536);
    const unsigned short* bufL = bufH + 16384;
    f32x4 acc[4];
#pragma unroll
    for (int js = 0; js < 4; ++js) acc[js] = (f32x4){0.f, 0.f, 0.f, 0.f};
#pragma unroll
    for (int kk = 0; kk < 8; ++kk) {
#pragma unroll
      for (int js = 0; js < 4; ++js) {
        int jj = js * 16 + l15;
        int e = jj * 256 + ((kk * 32 + lk * 8) ^ ((jj & 31) << 3));
        s16x8 bh = *reinterpret_cast<const s16x8*>(bufH + e);
        s16x8 bl = *reinterpret_cast<const s16x8*>(bufL + e);
        acc[js] = __builtin_amdgcn_mfma_f32_16x16x32_bf16(al[kk], bh, acc[js], 0, 0, 0);
        acc[js] = __builtin_amdgcn_mfma_f32_16x16x32_bf16(ah[kk], bl, acc[js], 0, 0, 0);
        acc[js] = __builtin_amdgcn_mfma_f32_16x16x32_bf16(ah[kk], bh, acc[js], 0, 0, 0);
      }
    }

    // top-2 update (ascending j -> first-index ties kept)
#pragma unroll
    for (int js = 0; js < 4; ++js) {
      int j = jt * 64 + js * 16 + l15;
      float Bj = BsL[j];
#pragma unroll
      for (int r = 0; r < 4; ++r) {
        float s = fmaf(-2.0f, acc[js][r], Bj);
        bool lt = s < b1v[r];
        float other = lt ? b1v[r] : s;
        b2v[r] = fminf(b2v[r], other);
        b1v[r] = fminf(b1v[r], s);
        b1i[r] = lt ? j : b1i[r];
      }
    }

    // write next tile into the other buffer, then barrier
    if (jt < 15) {
      unsigned short* bh2 = (unsigned short*)(ldsraw + ((jt + 1) & 1) * 65536);
      unsigned short* bl2 = bh2 + 16384;
#pragma unroll
      for (int i = 0; i < 4; ++i) {
        int idx = t + i * 512;
        int jj = idx >> 5, m = idx & 31;
        int e = jj * 256 + ((m * 8) ^ ((jj & 31) << 3));
        *reinterpret_cast<s16x8*>(bh2 + e) = sh[i];
        *reinterpret_cast<s16x8*>(bl2 + e) = sl[i];
      }
    }
    __syncthreads();
  }

  // merge top-2 across the 16 lanes sharing rows
#pragma unroll
  for (int mk = 1; mk < 16; mk <<= 1) {
#pragma unroll
    for (int r = 0; r < 4; ++r) {
      float ov1 = __shfl_xor(b1v[r], mk, 64);
      float ov2 = __shfl_xor(b2v[r], mk, 64);
      int oi1 = __shfl_xor(b1i[r], mk, 64);
      bool lt = ov1 < b1v[r];
      float hi = lt ? b1v[r] : ov1;
      b2v[r] = fminf(fminf(b2v[r], ov2), hi);
      b1v[r] = fminf(b1v[r], ov1);
      b1i[r] = lt ? oi1 : b1i[r];
    }
  }
  if (l15 == 0) {
#pragma unroll
    for (int r = 0; r < 4; ++r) {
      int rr = wv * 16 + lk * 4 + r;       // D row = (lane>>4)*4 + reg
      bestj[rr] = b1i[r];
      flg[rr] = (b2v[r] - b1v[r] <= M_GAP) ? 1 : 0;
    }
  }
  __syncthreads();

  if (t < 128) {
    int n = bid * 128 + t;
    idxo[n] = (float)bestj[t];             // provisional for flagged rows
    if (flg[t]) { unsigned pos = atomicAdd(cnt, 1u); list[pos] = (unsigned)n; }
  }

  // z_q gather + loss for unflagged rows (flagged handled by vq_exact)
  double lsum = 0.0;
#pragma unroll
  for (int i = 0; i < 16; ++i) {
    int idx4 = t + i * 512;                // 0..8191
    int p = idx4 >> 12;
    int c = (idx4 >> 4) & 255;
    int w4 = idx4 & 15;
    int bh = bid * 2 + p;
    size_t base = (size_t)(bh >> 6) * (256 * 4096) + (size_t)c * 4096 +
                  (size_t)(bh & 63) * 64 + (size_t)w4 * 4;
    float4 zv = *reinterpret_cast<const float4*>(z + base);
    float zz[4] = {zv.x, zv.y, zv.z, zv.w};
#pragma unroll
    for (int q = 0; q < 4; ++q) {
      int rr = p * 64 + w4 * 4 + q;
      if (!flg[rr]) {
        float cv = cb[(size_t)bestj[rr] * 256 + c];
        zq[base + q] = cv;
        double d = (double)cv - (double)zz[q];
        lsum += d * d;
      }
    }
  }
#pragma unroll
  for (int off = 32; off > 0; off >>= 1) lsum += __shfl_down(lsum, off, 64);
  if (lane == 0) wred[wv] = lsum;
  __syncthreads();
  if (t == 0) {
    double tot = 0.0;
#pragma unroll
    for (int i = 0; i < 8; ++i) tot += wred[i];
    atomicAdd(loss, (float)(tot * (1.25 / (double)NELEM)));
  }
}

// ---- exact np-chain rescore of flagged rows + their outputs ----
__global__ __launch_bounds__(256)
void vq_exact(const float* __restrict__ z, const float* __restrict__ cb,
              const float* __restrict__ Bsg, const unsigned* __restrict__ list,
              const unsigned* __restrict__ cnt, float* __restrict__ zq,
              float* __restrict__ loss, float* __restrict__ idxo) {
  __shared__ float zrow[256];
  __shared__ float Ash;
  __shared__ float rv[256];
  __shared__ int ri[256];
  const int t = threadIdx.x;
  const unsigned K = *cnt;
  for (unsigned it = blockIdx.x; it < K; it += gridDim.x) {
    int n = (int)list[it];
    int b = n >> 12;
    int hw = n & 4095;
    __syncthreads();   // protect shared reuse across iterations
    zrow[t] = z[(size_t)b * (256 * 4096) + (size_t)t * 4096 + hw];
    __syncthreads();
    if (t == 0) Ash = np_sumsq256(zrow, 1);
    __syncthreads();
    const float A = Ash;
    float acc[4] = {0.f, 0.f, 0.f, 0.f};
    const float* cbb = cb + (size_t)t * 4 * 256;
    const float4* z4 = reinterpret_cast<const float4*>(zrow);
    for (int c4 = 0; c4 < 64; ++c4) {
      float4 zv = z4[c4];
      float zz[4] = {zv.x, zv.y, zv.z, zv.w};
#pragma unroll
      for (int q = 0; q < 4; ++q) {
        float4 cv = reinterpret_cast<const float4*>(cbb + q * 256)[c4];
        acc[q] = fmaf(zz[0], cv.x, acc[q]);
        acc[q] = fmaf(zz[1], cv.y, acc[q]);
        acc[q] = fmaf(zz[2], cv.z, acc[q]);
        acc[q] = fmaf(zz[3], cv.w, acc[q]);
      }
    }
    float bv = 3.4e38f;
    int bi = 0;
#pragma unroll
    for (int q = 0; q < 4; ++q) {
      int j = t * 4 + q;
      float dd = __fsub_rn(__fadd_rn(A, Bsg[j]), __fmul_rn(2.0f, acc[q]));
      if (dd < bv) { bv = dd; bi = j; }
    }
    rv[t] = bv; ri[t] = bi;
    __syncthreads();
    for (int s2 = 128; s2 > 0; s2 >>= 1) {
      if (t < s2) {
        float v2 = rv[t + s2]; int i2 = ri[t + s2];
        if (v2 < rv[t] || (v2 == rv[t] && i2 < ri[t])) { rv[t] = v2; ri[t] = i2; }
      }
      __syncthreads();
    }
    const int jwin = ri[0];
    if (t == 0) idxo[n] = (float)jwin;
    float cv = cb[(size_t)jwin * 256 + t];
    zq[(size_t)b * (256 * 4096) + (size_t)t * 4096 + hw] = cv;
    float d = cv - zrow[t];
    __syncthreads();
    rv[t] = d * d;
    __syncthreads();
    for (int s2 = 128; s2 > 0; s2 >>= 1) {
      if (t < s2) rv[t] += rv[t + s2];
      __syncthreads();
    }
    if (t == 0) atomicAdd(loss, rv[0] * (1.25f / (float)NELEM));
  }
}

// ---- fallback (round-2 validated all-exact kernel) ----
__global__ __launch_bounds__(256)
void vq_ref(const float* __restrict__ z, const float* __restrict__ cb,
            float* __restrict__ zq, float* __restrict__ loss,
            float* __restrict__ idxo) {
  __shared__ __align__(16) float zt[256 * 64];
  __shared__ __align__(16) float cbt[256 * 64];
  __shared__ float As[64];
  __shared__ float Bs[64];
  __shared__ int bestj[64];
  __shared__ float cand_v[16 * 64];
  __shared__ int cand_i[16 * 64];
  __shared__ double wred[4];
  const int t = threadIdx.x;
  const int wg = t & 15, jg = t >> 4;
  const int bid = blockIdx.x;
  const int b = bid >> 6, h = bid & 63;
  const int n0 = bid * 64;
  const float4* z4 = reinterpret_cast<const float4*>(z + (size_t)b * 256 * 4096 + (size_t)h * 64);
  float4* zt4 = reinterpret_cast<float4*>(zt);
#pragma unroll
  for (int i = 0; i < 16; ++i) {
    int idx4 = t + i * 256;
    zt4[idx4] = z4[(size_t)(idx4 >> 4) * 1024 + (idx4 & 15)];
  }
  __syncthreads();
  if (t < 64) As[t] = np_sumsq256(zt + t, 64);
  float bv[4]; int bi[4];
#pragma unroll
  for (int a = 0; a < 4; ++a) { bv[a] = 3.4e38f; bi[a] = 0; }
  for (int p = 0; p < 16; ++p) {
    __syncthreads();
    const float4* cb4 = reinterpret_cast<const float4*>(cb) + (size_t)p * 64 * 64;
#pragma unroll
    for (int i = 0; i < 16; ++i) {
      int idx4 = t + i * 256;
      int jj = idx4 >> 6, c4 = idx4 & 63;
      float4 v = cb4[idx4];
      cbt[(c4 * 4 + 0) * 64 + jj] = v.x;
      cbt[(c4 * 4 + 1) * 64 + jj] = v.y;
      cbt[(c4 * 4 + 2) * 64 + jj] = v.z;
      cbt[(c4 * 4 + 3) * 64 + jj] = v.w;
    }
    __syncthreads();
    if (t < 64) Bs[t] = np_sumsq256(cbt + t, 64);
    float acc[4][4];
#pragma unroll
    for (int a = 0; a < 4; ++a)
#pragma unroll
      for (int u = 0; u < 4; ++u) acc[a][u] = 0.0f;
    const float4* ztp = reinterpret_cast<const float4*>(zt) + wg;
    const float4* cbp = reinterpret_cast<const float4*>(cbt) + jg;
#pragma unroll 4
    for (int c = 0; c < 256; ++c) {
      float4 zv = ztp[c * 16];
      float4 cv = cbp[c * 16];
      float za[4] = {zv.x, zv.y, zv.z, zv.w};
      float ca[4] = {cv.x, cv.y, cv.z, cv.w};
#pragma unroll
      for (int a = 0; a < 4; ++a)
#pragma unroll
        for (int u = 0; u < 4; ++u) acc[a][u] = fmaf(za[a], ca[u], acc[a][u]);
    }
    __syncthreads();
#pragma unroll
    for (int u = 0; u < 4; ++u) {
      int j = p * 64 + jg * 4 + u;
      float Bju = Bs[jg * 4 + u];
#pragma unroll
      for (int a = 0; a < 4; ++a) {
        float AB = __fadd_rn(As[wg * 4 + a], Bju);
        float dd = __fsub_rn(AB, __fmul_rn(2.0f, acc[a][u]));
        if (dd < bv[a]) { bv[a] = dd; bi[a] = j; }
      }
    }
  }
  __syncthreads();
#pragma unroll
  for (int a = 0; a < 4; ++a) {
    int w = wg * 4 + a;
    cand_v[jg * 64 + w] = bv[a];
    cand_i[jg * 64 + w] = bi[a];
  }
  __syncthreads();
  if (t < 64) {
    float v0 = cand_v[t]; int i0 = cand_i[t];
    for (int g = 1; g < 16; ++g) {
      float v = cand_v[g * 64 + t]; int ii = cand_i[g * 64 + t];
      if (v < v0 || (v == v0 && ii < i0)) { v0 = v; i0 = ii; }
    }
    bestj[t] = i0;
    idxo[n0 + t] = (float)i0;
  }
  __syncthreads();
  double lsum = 0.0;
  float* zqbase = zq + (size_t)b * 256 * 4096 + (size_t)h * 64;
  for (int i = 0; i < 64; ++i) {
    int idx = t + i * 256;
    int c = idx >> 6, w = idx & 63;
    float zvv = zt[c * 64 + w];
    float cvv = cb[(size_t)bestj[w] * 256 + c];
    zqbase[(size_t)c * 4096 + w] = cvv;
    double d = (double)cvv - (double)zvv;
    lsum += d * d;
  }
#pragma unroll
  for (int off = 32; off > 0; off >>= 1) lsum += __shfl_down(lsum, off, 64);
  if ((t & 63) == 0) wred[t >> 6] = lsum;
  __syncthreads();
  if (t == 0) {
    double tot = wred[0] + wred[1] + wred[2] + wred[3];
    atomicAdd(loss, (float)(tot * (1.25 / (double)NELEM)));
  }
}

extern "C" void kernel_launch(void* const* d_in, const int* in_sizes, int n_in,
                              void* d_out, int out_size, void* d_ws, size_t ws_size,
                              hipStream_t stream) {
  (void)in_sizes; (void)n_in; (void)out_size;
  const float* z = (const float*)d_in[0];
  const float* cb = (const float*)d_in[1];
  float* out = (float*)d_out;
  float* zq = out;
  float* loss = out + NELEM;
  float* idxo = out + NELEM + 1;
  if (ws_size < 1400000) {   // scratch too small: validated all-exact path
    hipMemsetAsync(loss, 0, sizeof(float), stream);
    vq_ref<<<512, 256, 0, stream>>>(z, cb, zq, loss, idxo);
    return;
  }
  unsigned char* ws = (unsigned char*)d_ws;
  unsigned* cnt = (unsigned*)ws;                       // 4 B
  float* Bsg = (float*)(ws + 1024);                    // 4 KB
  unsigned* list = (unsigned*)(ws + 8192);             // 128 KB
  unsigned short* cbh = (unsigned short*)(ws + 139264);  // 512 KB
  unsigned short* cbl = (unsigned short*)(ws + 663552);  // 512 KB
  vq_prep<<<16, 256, 0, stream>>>(cb, cbh, cbl, Bsg, cnt, loss);
  vq_fast<<<256, 512, 0, stream>>>(z, cb, cbh, cbl, Bsg, zq, loss, idxo, list, cnt);
  vq_exact<<<256, 256, 0, stream>>>(z, cb, Bsg, list, cnt, zq, loss, idxo);
}

// Round 5
// 124.173 us; speedup vs baseline: 5.7644x; 1.4277x over previous
//
#include <hip/hip_runtime.h>

#define NELEM 8388608    // 8*256*64*64
#define M_GAP 8e-5f

typedef short s16x8 __attribute__((ext_vector_type(8)));
typedef float f32x4 __attribute__((ext_vector_type(4)));

__device__ __forceinline__ unsigned short bf16r(float f) {
  unsigned u = __float_as_uint(f);
  return (unsigned short)((u + 0x7fffu + ((u >> 16) & 1u)) >> 16);
}
__device__ __forceinline__ float bf16f(unsigned short h) {
  return __uint_as_float(((unsigned)h) << 16);
}

// numpy pairwise sum of squares, 128-block: 8 accumulators stride 8,
// combined ((r0+r1)+(r2+r3))+((r4+r5)+(r6+r7)). All single-rounded f32.
__device__ __forceinline__ float pw128_sq(const float* p, int s) {
  float r[8];
#pragma unroll
  for (int j = 0; j < 8; ++j) { float v = p[j * s]; r[j] = __fmul_rn(v, v); }
#pragma unroll
  for (int i = 8; i < 128; i += 8) {
#pragma unroll
    for (int j = 0; j < 8; ++j) {
      float v = p[(i + j) * s];
      r[j] = __fadd_rn(r[j], __fmul_rn(v, v));
    }
  }
  return __fadd_rn(__fadd_rn(__fadd_rn(r[0], r[1]), __fadd_rn(r[2], r[3])),
                   __fadd_rn(__fadd_rn(r[4], r[5]), __fadd_rn(r[6], r[7])));
}
__device__ __forceinline__ float np_sumsq256(const float* p, int s) {
  return __fadd_rn(pw128_sq(p, s), pw128_sq(p + 128 * s, s));
}

// ---- prep: pre-swizzled bf16 h/l codebook image + f32 transpose + norms ----
// cbimg layout per 64-code tile jt (65536 B): h-plane shorts [0,16384):
//   img[jj*256 + (c ^ ((jj&31)<<3))], l-plane at +16384 shorts.
__global__ __launch_bounds__(256)
void vq_prep(const float* __restrict__ cb, unsigned short* __restrict__ cbimg,
             float* __restrict__ cbT, float* __restrict__ Bsg,
             unsigned* __restrict__ cnt, float* __restrict__ loss) {
  int gid = blockIdx.x * 256 + threadIdx.x;   // 0..4095
  if (gid == 0) { *cnt = 0u; *loss = 0.0f; }
  int j = gid >> 2, qt = gid & 3;
  const float4* row4 = reinterpret_cast<const float4*>(cb + (size_t)j * 256 + qt * 64);
  int jt = j >> 6, jj = j & 63;
  unsigned short* baseh = cbimg + (size_t)jt * 32768 + jj * 256;
  unsigned short* basel = baseh + 16384;
  int sw = (jj & 31) << 3;
#pragma unroll
  for (int m = 0; m < 8; ++m) {               // 8 consecutive c per group
    int c0 = qt * 64 + m * 8;
    float4 va = row4[m * 2];
    float4 vb = row4[m * 2 + 1];
    float v[8] = {va.x, va.y, va.z, va.w, vb.x, vb.y, vb.z, vb.w};
    s16x8 hv, lv;
#pragma unroll
    for (int q = 0; q < 8; ++q) {
      unsigned short h = bf16r(v[q]);
      hv[q] = (short)h;
      lv[q] = (short)bf16r(v[q] - bf16f(h));
      cbT[(size_t)(c0 + q) * 1024 + j] = v[q];
    }
    int e = c0 ^ sw;                          // c0 8-aligned, sw bits 3..7
    *reinterpret_cast<s16x8*>(baseh + e) = hv;
    *reinterpret_cast<s16x8*>(basel + e) = lv;
  }
  if (qt == 0) Bsg[j] = np_sumsq256(cb + (size_t)j * 256, 1);
}

// ---- fast: 4 waves x 32 rows, MFMA scoring, dbuf linear-copy B staging ----
__global__ __launch_bounds__(256, 1)
void vq_fast(const float* __restrict__ z, const float* __restrict__ cb,
             const unsigned short* __restrict__ cbimg,
             const float* __restrict__ Bsg,
             float* __restrict__ zq, float* __restrict__ loss,
             float* __restrict__ idxo,
             unsigned* __restrict__ list, unsigned* __restrict__ cnt) {
  __shared__ __align__(16) unsigned char buf[131072];  // 2 x 64KB B tiles / zt / ldsF
  __shared__ float BsL[1024];
  __shared__ float part[16][64];
  __shared__ float rowA[128];
  __shared__ int bestj[128];
  __shared__ float bestd[128];
  __shared__ unsigned char flg[128];
  __shared__ float wred[4];

  const int t = threadIdx.x;
  const int bid = blockIdx.x;          // rows n0 = bid*128
  const int lane = t & 63;
  const int wv = t >> 6;               // wave 0..3, rows wv*32..+31
  const int l15 = lane & 15;
  const int lk = lane >> 4;            // 0..3

  float* zt = reinterpret_cast<float*>(buf);   // [256][65] f32 during A-stage

  s16x8 ah[2][8], al[2][8];            // two 16-row tiles per wave

  // ---- A staging in halves (64 rows each = one (b,h) pair) ----
  for (int hp = 0; hp < 2; ++hp) {
    int bh = bid * 2 + hp;
    const float4* z4 = reinterpret_cast<const float4*>(
        z + (size_t)(bh >> 6) * 1048576 + (size_t)(bh & 63) * 64);
    float sq[4] = {0.f, 0.f, 0.f, 0.f};
#pragma unroll
    for (int i = 0; i < 16; ++i) {
      int idx = t + i * 256;           // c = idx>>4 (=(t>>4)+16i), w4 = t&15
      int c = idx >> 4, w4 = idx & 15;
      float4 v = z4[(size_t)c * 1024 + w4];
      zt[c * 65 + w4 * 4 + 0] = v.x;
      zt[c * 65 + w4 * 4 + 1] = v.y;
      zt[c * 65 + w4 * 4 + 2] = v.z;
      zt[c * 65 + w4 * 4 + 3] = v.w;
      sq[0] += v.x * v.x; sq[1] += v.y * v.y;
      sq[2] += v.z * v.z; sq[3] += v.w * v.w;
    }
#pragma unroll
    for (int q = 0; q < 4; ++q) part[t >> 4][(t & 15) * 4 + q] = sq[q];
    __syncthreads();
    if (t < 64) {
      float s = 0.f;
#pragma unroll
      for (int g = 0; g < 16; ++g) s += part[g][t];
      rowA[hp * 64 + t] = s;
    }
    // waves owning this half preload their a-frags from zt
    if ((wv >> 1) == hp) {
#pragma unroll
      for (int rs = 0; rs < 2; ++rs) {
        int lr = (wv & 1) * 32 + rs * 16 + l15;   // local row in half
#pragma unroll
        for (int kk = 0; kk < 8; ++kk) {
#pragma unroll
          for (int m = 0; m < 8; ++m) {
            float f = zt[(kk * 32 + lk * 8 + m) * 65 + lr];
            unsigned short h = bf16r(f);
            ah[rs][kk][m] = (short)h;
            al[rs][kk][m] = (short)bf16r(f - bf16f(h));
          }
        }
      }
    }
    __syncthreads();
  }

  // ---- stage B tile 0 (linear copy; swizzle is baked into cbimg) ----
#pragma unroll
  for (int i = 0; i < 16; ++i) {
    int item = t + i * 256;
    *reinterpret_cast<s16x8*>(buf + item * 16) =
        *reinterpret_cast<const s16x8*>((const unsigned char*)cbimg + item * 16);
  }
  for (int i = t; i < 1024; i += 256) BsL[i] = Bsg[i];
  __syncthreads();

  float b1v[2][4], b2v[2][4];
  int b1i[2][4];
#pragma unroll
  for (int rs = 0; rs < 2; ++rs)
#pragma unroll
    for (int r = 0; r < 4; ++r) { b1v[rs][r] = 3.4e38f; b2v[rs][r] = 3.4e38f; b1i[rs][r] = 0; }

  for (int jt = 0; jt < 16; ++jt) {
    const unsigned short* bufH = reinterpret_cast<const unsigned short*>(buf + (jt & 1) * 65536);
    const unsigned short* bufL = bufH + 16384;
    unsigned char* nbuf = buf + ((jt + 1) & 1) * 65536;
    const unsigned char* nsrc = (const unsigned char*)cbimg + (size_t)(jt + 1) * 65536;

    f32x4 acc[2][4];
#pragma unroll
    for (int rs = 0; rs < 2; ++rs)
#pragma unroll
      for (int js = 0; js < 4; ++js) acc[rs][js] = (f32x4){0.f, 0.f, 0.f, 0.f};

    s16x8 g0, g1, g2, g3;
#pragma unroll
    for (int kk = 0; kk < 8; ++kk) {
      if (jt < 15 && (kk & 1) == 0) {          // issue prefetch batch kk/2
        int b = kk >> 1;
        g0 = *reinterpret_cast<const s16x8*>(nsrc + (t + b * 1024 + 0) * 16);
        g1 = *reinterpret_cast<const s16x8*>(nsrc + (t + b * 1024 + 256) * 16);
        g2 = *reinterpret_cast<const s16x8*>(nsrc + (t + b * 1024 + 512) * 16);
        g3 = *reinterpret_cast<const s16x8*>(nsrc + (t + b * 1024 + 768) * 16);
      }
#pragma unroll
      for (int js = 0; js < 4; ++js) {
        int jj = js * 16 + l15;
        int e = jj * 256 + ((kk * 32 + lk * 8) ^ ((jj & 31) << 3));
        s16x8 bh = *reinterpret_cast<const s16x8*>(bufH + e);
        s16x8 bl = *reinterpret_cast<const s16x8*>(bufL + e);
#pragma unroll
        for (int rs = 0; rs < 2; ++rs) {
          acc[rs][js] = __builtin_amdgcn_mfma_f32_16x16x32_bf16(al[rs][kk], bh, acc[rs][js], 0, 0, 0);
          acc[rs][js] = __builtin_amdgcn_mfma_f32_16x16x32_bf16(ah[rs][kk], bl, acc[rs][js], 0, 0, 0);
          acc[rs][js] = __builtin_amdgcn_mfma_f32_16x16x32_bf16(ah[rs][kk], bh, acc[rs][js], 0, 0, 0);
        }
      }
      if (jt < 15 && (kk & 1) == 1) {          // commit prefetch batch
        int b = kk >> 1;
        *reinterpret_cast<s16x8*>(nbuf + (t + b * 1024 + 0) * 16) = g0;
        *reinterpret_cast<s16x8*>(nbuf + (t + b * 1024 + 256) * 16) = g1;
        *reinterpret_cast<s16x8*>(nbuf + (t + b * 1024 + 512) * 16) = g2;
        *reinterpret_cast<s16x8*>(nbuf + (t + b * 1024 + 768) * 16) = g3;
      }
    }

    // top-2 update (ascending j -> first-index ties kept)
#pragma unroll
    for (int js = 0; js < 4; ++js) {
      int j = jt * 64 + js * 16 + l15;
      float Bj = BsL[j];
#pragma unroll
      for (int rs = 0; rs < 2; ++rs)
#pragma unroll
        for (int r = 0; r < 4; ++r) {
          float s = fmaf(-2.0f, acc[rs][js][r], Bj);
          bool lt = s < b1v[rs][r];
          float other = lt ? b1v[rs][r] : s;
          b2v[rs][r] = fminf(b2v[rs][r], other);
          b1v[rs][r] = fminf(b1v[rs][r], s);
          b1i[rs][r] = lt ? j : b1i[rs][r];
        }
    }
    __syncthreads();
  }

  // merge top-2 across the 16 lanes sharing rows
#pragma unroll
  for (int mk = 1; mk < 16; mk <<= 1) {
#pragma unroll
    for (int rs = 0; rs < 2; ++rs)
#pragma unroll
      for (int r = 0; r < 4; ++r) {
        float ov1 = __shfl_xor(b1v[rs][r], mk, 64);
        float ov2 = __shfl_xor(b2v[rs][r], mk, 64);
        int oi1 = __shfl_xor(b1i[rs][r], mk, 64);
        bool lt = ov1 < b1v[rs][r];
        float hi = lt ? b1v[rs][r] : ov1;
        b2v[rs][r] = fminf(fminf(b2v[rs][r], ov2), hi);
        b1v[rs][r] = fminf(b1v[rs][r], ov1);
        b1i[rs][r] = lt ? oi1 : b1i[rs][r];
      }
  }
  if (l15 == 0) {
#pragma unroll
    for (int rs = 0; rs < 2; ++rs)
#pragma unroll
      for (int r = 0; r < 4; ++r) {
        int rr = wv * 32 + rs * 16 + lk * 4 + r;   // D row = (lane>>4)*4 + reg
        bestj[rr] = b1i[rs][r];
        bestd[rr] = b1v[rs][r];
        flg[rr] = (b2v[rs][r] - b1v[rs][r] <= M_GAP) ? 1 : 0;
      }
  }
  __syncthreads();

  if (t < 128) {
    int n = bid * 128 + t;
    idxo[n] = (float)bestj[t];                 // provisional for flagged rows
    if (flg[t]) { unsigned pos = atomicAdd(cnt, 1u); list[pos] = (unsigned)n; }
  }

  // loss for unflagged rows: dist^2 = rowA + s_best  (tolerance is huge)
  {
    float lv = 0.f;
    if (t < 128 && !flg[t]) lv = rowA[t] + bestd[t];
#pragma unroll
    for (int off = 32; off > 0; off >>= 1) lv += __shfl_down(lv, off, 64);
    if (lane == 0) wred[wv] = lv;
  }
  __syncthreads();
  if (t == 0) {
    float tot = wred[0] + wred[1] + wred[2] + wred[3];
    atomicAdd(loss, tot * (1.25f / (float)NELEM));
  }

  // ---- zq gather: row-major float4 gather -> LDS transpose -> coalesced write
  f32x4* ldsF4 = reinterpret_cast<f32x4*>(buf);
  const float4* cb4 = reinterpret_cast<const float4*>(cb);
#pragma unroll
  for (int i = 0; i < 32; ++i) {
    int item = t + i * 256;            // rr = item>>6 (uniform per wave-instr)
    int rr = item >> 6, cc = item & 63;
    float4 v = cb4[(size_t)bestj[rr] * 64 + cc];
    ldsF4[rr * 64 + (cc ^ ((rr >> 2) & 7))] = (f32x4){v.x, v.y, v.z, v.w};
  }
  __syncthreads();
  const float* ldsF = reinterpret_cast<const float*>(buf);
#pragma unroll
  for (int i = 0; i < 32; ++i) {
    int item = t + i * 256;            // w4q = t&31, c = (t>>5) + 8i
    int w4q = item & 31, c = item >> 5;
    float ov[4];
#pragma unroll
    for (int q = 0; q < 4; ++q) {
      int rr = w4q * 4 + q;
      ov[q] = ldsF[(rr * 64 + ((c >> 2) ^ ((rr >> 2) & 7))) * 4 + (c & 3)];
    }
    int bh = bid * 2 + (w4q >> 4);
    size_t base = (size_t)(bh >> 6) * 1048576 + (size_t)c * 4096 +
                  (size_t)(bh & 63) * 64 + (size_t)(w4q & 15) * 4;
    *reinterpret_cast<float4*>(zq + base) = make_float4(ov[0], ov[1], ov[2], ov[3]);
  }
}

// ---- exact np-chain rescore of flagged rows (coalesced via cbT) ----
__global__ __launch_bounds__(256)
void vq_exact(const float* __restrict__ z, const float* __restrict__ cb,
              const float* __restrict__ cbT, const float* __restrict__ Bsg,
              const unsigned* __restrict__ list, const unsigned* __restrict__ cnt,
              float* __restrict__ zq, float* __restrict__ loss,
              float* __restrict__ idxo) {
  __shared__ float zrow[256];
  __shared__ float Ash;
  __shared__ float rv[256];
  __shared__ int ri[256];
  const int t = threadIdx.x;
  const unsigned K = *cnt;
  const float4* cbT4 = reinterpret_cast<const float4*>(cbT);
  for (unsigned it = blockIdx.x; it < K; it += gridDim.x) {
    int n = (int)list[it];
    int b = n >> 12;
    int hw = n & 4095;
    __syncthreads();   // protect shared reuse across iterations
    zrow[t] = z[(size_t)b * 1048576 + (size_t)t * 4096 + hw];
    __syncthreads();
    if (t == 0) Ash = np_sumsq256(zrow, 1);
    __syncthreads();
    const float A = Ash;
    // 4 sequential-fmaf chains (c ascending), j = 4t..4t+3, coalesced loads
    float acc[4] = {0.f, 0.f, 0.f, 0.f};
    for (int c = 0; c < 256; ++c) {
      float zc = zrow[c];
      float4 v = cbT4[c * 256 + t];
      acc[0] = fmaf(zc, v.x, acc[0]);
      acc[1] = fmaf(zc, v.y, acc[1]);
      acc[2] = fmaf(zc, v.z, acc[2]);
      acc[3] = fmaf(zc, v.w, acc[3]);
    }
    float bv = 3.4e38f;
    int bi = 0;
#pragma unroll
    for (int q = 0; q < 4; ++q) {
      int j = t * 4 + q;
      float dd = __fsub_rn(__fadd_rn(A, Bsg[j]), __fmul_rn(2.0f, acc[q]));
      if (dd < bv) { bv = dd; bi = j; }
    }
    rv[t] = bv; ri[t] = bi;
    __syncthreads();
    for (int s2 = 128; s2 > 0; s2 >>= 1) {
      if (t < s2) {
        float v2 = rv[t + s2]; int i2 = ri[t + s2];
        if (v2 < rv[t] || (v2 == rv[t] && i2 < ri[t])) { rv[t] = v2; ri[t] = i2; }
      }
      __syncthreads();
    }
    const int jwin = ri[0];
    if (t == 0) idxo[n] = (float)jwin;
    float cv = cb[(size_t)jwin * 256 + t];
    zq[(size_t)b * 1048576 + (size_t)t * 4096 + hw] = cv;
    float d = cv - zrow[t];
    __syncthreads();
    rv[t] = d * d;
    __syncthreads();
    for (int s2 = 128; s2 > 0; s2 >>= 1) {
      if (t < s2) rv[t] += rv[t + s2];
      __syncthreads();
    }
    if (t == 0) atomicAdd(loss, rv[0] * (1.25f / (float)NELEM));
  }
}

// ---- fallback (round-2 validated all-exact kernel) ----
__global__ __launch_bounds__(256)
void vq_ref(const float* __restrict__ z, const float* __restrict__ cb,
            float* __restrict__ zq, float* __restrict__ loss,
            float* __restrict__ idxo) {
  __shared__ __align__(16) float zt[256 * 64];
  __shared__ __align__(16) float cbt[256 * 64];
  __shared__ float As[64];
  __shared__ float Bs[64];
  __shared__ int bestj[64];
  __shared__ float cand_v[16 * 64];
  __shared__ int cand_i[16 * 64];
  __shared__ double wred[4];
  const int t = threadIdx.x;
  const int wg = t & 15, jg = t >> 4;
  const int bid = blockIdx.x;
  const int b = bid >> 6, h = bid & 63;
  const int n0 = bid * 64;
  const float4* z4 = reinterpret_cast<const float4*>(z + (size_t)b * 256 * 4096 + (size_t)h * 64);
  float4* zt4 = reinterpret_cast<float4*>(zt);
#pragma unroll
  for (int i = 0; i < 16; ++i) {
    int idx4 = t + i * 256;
    zt4[idx4] = z4[(size_t)(idx4 >> 4) * 1024 + (idx4 & 15)];
  }
  __syncthreads();
  if (t < 64) As[t] = np_sumsq256(zt + t, 64);
  float bv[4]; int bi[4];
#pragma unroll
  for (int a = 0; a < 4; ++a) { bv[a] = 3.4e38f; bi[a] = 0; }
  for (int p = 0; p < 16; ++p) {
    __syncthreads();
    const float4* cb4 = reinterpret_cast<const float4*>(cb) + (size_t)p * 64 * 64;
#pragma unroll
    for (int i = 0; i < 16; ++i) {
      int idx4 = t + i * 256;
      int jj = idx4 >> 6, c4 = idx4 & 63;
      float4 v = cb4[idx4];
      cbt[(c4 * 4 + 0) * 64 + jj] = v.x;
      cbt[(c4 * 4 + 1) * 64 + jj] = v.y;
      cbt[(c4 * 4 + 2) * 64 + jj] = v.z;
      cbt[(c4 * 4 + 3) * 64 + jj] = v.w;
    }
    __syncthreads();
    if (t < 64) Bs[t] = np_sumsq256(cbt + t, 64);
    float acc[4][4];
#pragma unroll
    for (int a = 0; a < 4; ++a)
#pragma unroll
      for (int u = 0; u < 4; ++u) acc[a][u] = 0.0f;
    const float4* ztp = reinterpret_cast<const float4*>(zt) + wg;
    const float4* cbp = reinterpret_cast<const float4*>(cbt) + jg;
#pragma unroll 4
    for (int c = 0; c < 256; ++c) {
      float4 zv = ztp[c * 16];
      float4 cv = cbp[c * 16];
      float za[4] = {zv.x, zv.y, zv.z, zv.w};
      float ca[4] = {cv.x, cv.y, cv.z, cv.w};
#pragma unroll
      for (int a = 0; a < 4; ++a)
#pragma unroll
        for (int u = 0; u < 4; ++u) acc[a][u] = fmaf(za[a], ca[u], acc[a][u]);
    }
    __syncthreads();
#pragma unroll
    for (int u = 0; u < 4; ++u) {
      int j = p * 64 + jg * 4 + u;
      float Bju = Bs[jg * 4 + u];
#pragma unroll
      for (int a = 0; a < 4; ++a) {
        float AB = __fadd_rn(As[wg * 4 + a], Bju);
        float dd = __fsub_rn(AB, __fmul_rn(2.0f, acc[a][u]));
        if (dd < bv[a]) { bv[a] = dd; bi[a] = j; }
      }
    }
  }
  __syncthreads();
#pragma unroll
  for (int a = 0; a < 4; ++a) {
    int w = wg * 4 + a;
    cand_v[jg * 64 + w] = bv[a];
    cand_i[jg * 64 + w] = bi[a];
  }
  __syncthreads();
  if (t < 64) {
    float v0 = cand_v[t]; int i0 = cand_i[t];
    for (int g = 1; g < 16; ++g) {
      float v = cand_v[g * 64 + t]; int ii = cand_i[g * 64 + t];
      if (v < v0 || (v == v0 && ii < i0)) { v0 = v; i0 = ii; }
    }
    bestj[t] = i0;
    idxo[n0 + t] = (float)i0;
  }
  __syncthreads();
  double lsum = 0.0;
  float* zqbase = zq + (size_t)b * 256 * 4096 + (size_t)h * 64;
  for (int i = 0; i < 64; ++i) {
    int idx = t + i * 256;
    int c = idx >> 6, w = idx & 63;
    float zvv = zt[c * 64 + w];
    float cvv = cb[(size_t)bestj[w] * 256 + c];
    zqbase[(size_t)c * 4096 + w] = cvv;
    double d = (double)cvv - (double)zvv;
    lsum += d * d;
  }
#pragma unroll
  for (int off = 32; off > 0; off >>= 1) lsum += __shfl_down(lsum, off, 64);
  if ((t & 63) == 0) wred[t >> 6] = lsum;
  __syncthreads();
  if (t == 0) {
    double tot = wred[0] + wred[1] + wred[2] + wred[3];
    atomicAdd(loss, (float)(tot * (1.25 / (double)NELEM)));
  }
}

extern "C" void kernel_launch(void* const* d_in, const int* in_sizes, int n_in,
                              void* d_out, int out_size, void* d_ws, size_t ws_size,
                              hipStream_t stream) {
  (void)in_sizes; (void)n_in; (void)out_size;
  const float* z = (const float*)d_in[0];
  const float* cb = (const float*)d_in[1];
  float* out = (float*)d_out;
  float* zq = out;
  float* loss = out + NELEM;
  float* idxo = out + NELEM + 1;
  if (ws_size < 2236416) {   // scratch too small: validated all-exact path
    hipMemsetAsync(loss, 0, sizeof(float), stream);
    vq_ref<<<512, 256, 0, stream>>>(z, cb, zq, loss, idxo);
    return;
  }
  unsigned char* ws = (unsigned char*)d_ws;
  unsigned* cnt = (unsigned*)ws;                             // 4 B
  float* Bsg = (float*)(ws + 1024);                          // 4 KB
  unsigned* list = (unsigned*)(ws + 8192);                   // 128 KB
  float* cbT = (float*)(ws + 139264);                        // 1 MB
  unsigned short* cbimg = (unsigned short*)(ws + 1187840);   // 1 MB
  vq_prep<<<16, 256, 0, stream>>>(cb, cbimg, cbT, Bsg, cnt, loss);
  vq_fast<<<256, 256, 0, stream>>>(z, cb, cbimg, Bsg, zq, loss, idxo, list, cnt);
  vq_exact<<<256, 256, 0, stream>>>(z, cb, cbT, Bsg, list, cnt, zq, loss, idxo);
}

// Round 6
// 103.771 us; speedup vs baseline: 6.8978x; 1.1966x over previous
//
#include <hip/hip_runtime.h>
#include <hip/hip_fp16.h>

#define NELEM 8388608    // 8*256*64*64
#define M_GAP 6e-4f
#define SCORE_SCALE (-1.0f / 512.0f)   // s = B - 2*(acc/1024)

typedef _Float16 f16x8 __attribute__((ext_vector_type(8)));
typedef short s16x8 __attribute__((ext_vector_type(8)));
typedef float f32x4 __attribute__((ext_vector_type(4)));

// numpy pairwise sum of squares, 128-block: 8 accumulators stride 8,
// combined ((r0+r1)+(r2+r3))+((r4+r5)+(r6+r7)). All single-rounded f32.
__device__ __forceinline__ float pw128_sq(const float* p, int s) {
  float r[8];
#pragma unroll
  for (int j = 0; j < 8; ++j) { float v = p[j * s]; r[j] = __fmul_rn(v, v); }
#pragma unroll
  for (int i = 8; i < 128; i += 8) {
#pragma unroll
    for (int j = 0; j < 8; ++j) {
      float v = p[(i + j) * s];
      r[j] = __fadd_rn(r[j], __fmul_rn(v, v));
    }
  }
  return __fadd_rn(__fadd_rn(__fadd_rn(r[0], r[1]), __fadd_rn(r[2], r[3])),
                   __fadd_rn(__fadd_rn(r[4], r[5]), __fadd_rn(r[6], r[7])));
}
__device__ __forceinline__ float np_sumsq256(const float* p, int s) {
  return __fadd_rn(pw128_sq(p, s), pw128_sq(p + 128 * s, s));
}

// ---- prep: pre-swizzled fp16 codebook image (x1024) + f32 transpose + norms
// cbimg per 64-code tile jt (32768 B = 16384 shorts):
//   img[jj*256 + (c ^ ((jj&31)<<3))]  (half-word units)
__global__ __launch_bounds__(256)
void vq_prep(const float* __restrict__ cb, unsigned short* __restrict__ cbimg,
             float* __restrict__ cbT, float* __restrict__ Bsg,
             unsigned* __restrict__ cnt, float* __restrict__ loss) {
  int gid = blockIdx.x * 256 + threadIdx.x;   // 0..4095
  if (gid == 0) { *cnt = 0u; *loss = 0.0f; }
  int j = gid >> 2, qt = gid & 3;
  const float4* row4 = reinterpret_cast<const float4*>(cb + (size_t)j * 256 + qt * 64);
  int jt = j >> 6, jj = j & 63;
  unsigned short* baseh = cbimg + (size_t)jt * 16384 + jj * 256;
  int sw = (jj & 31) << 3;
#pragma unroll
  for (int m = 0; m < 8; ++m) {               // 8 consecutive c per group
    int c0 = qt * 64 + m * 8;
    float4 va = row4[m * 2];
    float4 vb = row4[m * 2 + 1];
    float v[8] = {va.x, va.y, va.z, va.w, vb.x, vb.y, vb.z, vb.w};
    s16x8 hv;
#pragma unroll
    for (int q = 0; q < 8; ++q) {
      hv[q] = (short)__half_as_ushort(__float2half(v[q] * 1024.0f));  // RNE
      cbT[(size_t)(c0 + q) * 1024 + j] = v[q];
    }
    int e = c0 ^ sw;                          // c0 8-aligned, sw bits 3..7
    *reinterpret_cast<s16x8*>(baseh + e) = hv;
  }
  if (qt == 0) Bsg[j] = np_sumsq256(cb + (size_t)j * 256, 1);
}

// ---- fast: 512 blocks x 64 rows, 4 waves x 16 rows, fp16 MFMA, 2 blk/CU ----
__global__ __launch_bounds__(256, 2)
void vq_fast(const float* __restrict__ z, const float* __restrict__ cb,
             const unsigned short* __restrict__ cbimg,
             const float* __restrict__ Bsg,
             float* __restrict__ zq, float* __restrict__ loss,
             float* __restrict__ idxo,
             unsigned* __restrict__ list, unsigned* __restrict__ cnt) {
  __shared__ __align__(16) unsigned char buf[66560];  // zt[256][65]f32 / 2x32KB B / ldsF
  __shared__ float BsL[1024];
  __shared__ float part[16][64];
  __shared__ float rowA[64];
  __shared__ int bestj[64];
  __shared__ float bestd[64];
  __shared__ unsigned char flg[64];
  __shared__ float wred[4];

  const int t = threadIdx.x;
  const int bid = blockIdx.x;          // = bh; rows n0 = bid*64
  const int lane = t & 63;
  const int wv = t >> 6;               // wave 0..3, rows wv*16..+15
  const int l15 = lane & 15;
  const int lk = lane >> 4;            // 0..3

  float* zt = reinterpret_cast<float*>(buf);   // [256 c][65] f32 during A-stage

  // ---- A staging: one (b,h): zt[c][w] + simple-sum row norms ----
  const float4* z4 = reinterpret_cast<const float4*>(
      z + (size_t)(bid >> 6) * 1048576 + (size_t)(bid & 63) * 64);
  {
    float sq[4] = {0.f, 0.f, 0.f, 0.f};
#pragma unroll
    for (int i = 0; i < 16; ++i) {
      int idx = t + i * 256;           // c = idx>>4, w4 = t&15
      int c = idx >> 4, w4 = idx & 15;
      float4 v = z4[(size_t)c * 1024 + w4];
      zt[c * 65 + w4 * 4 + 0] = v.x;
      zt[c * 65 + w4 * 4 + 1] = v.y;
      zt[c * 65 + w4 * 4 + 2] = v.z;
      zt[c * 65 + w4 * 4 + 3] = v.w;
      sq[0] += v.x * v.x; sq[1] += v.y * v.y;
      sq[2] += v.z * v.z; sq[3] += v.w * v.w;
    }
#pragma unroll
    for (int q = 0; q < 4; ++q) part[t >> 4][(t & 15) * 4 + q] = sq[q];
  }
  __syncthreads();
  if (t < 64) {
    float s = 0.f;
#pragma unroll
    for (int g = 0; g < 16; ++g) s += part[g][t];
    rowA[t] = s;
  }

  // a-frags: row = wv*16 + l15, k = kk*32 + lk*8 + m  (fp16 RNE)
  const int arow = wv * 16 + l15;
  f16x8 ah[8];
#pragma unroll
  for (int kk = 0; kk < 8; ++kk)
#pragma unroll
    for (int m = 0; m < 8; ++m)
      ah[kk][m] = (_Float16)zt[(kk * 32 + lk * 8 + m) * 65 + arow];
  __syncthreads();   // zt reads done; buf free for B tiles

  // stage B tile 0 (linear copy; swizzle baked into cbimg)
#pragma unroll
  for (int i = 0; i < 8; ++i) {
    int item = t + i * 256;            // 0..2047 s16x8 items
    *reinterpret_cast<s16x8*>(buf + item * 16) =
        *reinterpret_cast<const s16x8*>((const unsigned char*)cbimg + item * 16);
  }
  for (int i = t; i < 1024; i += 256) BsL[i] = Bsg[i];
  __syncthreads();

  float b1v[4], b2v[4];
  int b1i[4];
#pragma unroll
  for (int r = 0; r < 4; ++r) { b1v[r] = 3.4e38f; b2v[r] = 3.4e38f; b1i[r] = 0; }

  for (int jt = 0; jt < 16; ++jt) {
    const unsigned short* bufH = reinterpret_cast<const unsigned short*>(buf + (jt & 1) * 32768);
    unsigned char* nbuf = buf + ((jt + 1) & 1) * 32768;
    const unsigned char* nsrc = (const unsigned char*)cbimg + (size_t)(jt + 1) * 32768;

    f32x4 acc[4];
#pragma unroll
    for (int js = 0; js < 4; ++js) acc[js] = (f32x4){0.f, 0.f, 0.f, 0.f};

    s16x8 g0, g1, g2, g3, g4, g5, g6, g7;
#pragma unroll
    for (int kk = 0; kk < 8; ++kk) {
      if (jt < 15) {
        if (kk == 0) {
          g0 = *reinterpret_cast<const s16x8*>(nsrc + (t + 0) * 16);
          g1 = *reinterpret_cast<const s16x8*>(nsrc + (t + 256) * 16);
          g2 = *reinterpret_cast<const s16x8*>(nsrc + (t + 512) * 16);
          g3 = *reinterpret_cast<const s16x8*>(nsrc + (t + 768) * 16);
        } else if (kk == 2) {
          g4 = *reinterpret_cast<const s16x8*>(nsrc + (t + 1024) * 16);
          g5 = *reinterpret_cast<const s16x8*>(nsrc + (t + 1280) * 16);
          g6 = *reinterpret_cast<const s16x8*>(nsrc + (t + 1536) * 16);
          g7 = *reinterpret_cast<const s16x8*>(nsrc + (t + 1792) * 16);
        }
      }
#pragma unroll
      for (int js = 0; js < 4; ++js) {
        int jj = js * 16 + l15;
        int e = jj * 256 + ((kk * 32 + lk * 8) ^ ((jj & 31) << 3));
        f16x8 bh = *reinterpret_cast<const f16x8*>(bufH + e);
        acc[js] = __builtin_amdgcn_mfma_f32_16x16x32_f16(ah[kk], bh, acc[js], 0, 0, 0);
      }
      if (jt < 15) {
        if (kk == 4) {
          *reinterpret_cast<s16x8*>(nbuf + (t + 0) * 16) = g0;
          *reinterpret_cast<s16x8*>(nbuf + (t + 256) * 16) = g1;
          *reinterpret_cast<s16x8*>(nbuf + (t + 512) * 16) = g2;
          *reinterpret_cast<s16x8*>(nbuf + (t + 768) * 16) = g3;
        } else if (kk == 6) {
          *reinterpret_cast<s16x8*>(nbuf + (t + 1024) * 16) = g4;
          *reinterpret_cast<s16x8*>(nbuf + (t + 1280) * 16) = g5;
          *reinterpret_cast<s16x8*>(nbuf + (t + 1536) * 16) = g6;
          *reinterpret_cast<s16x8*>(nbuf + (t + 1792) * 16) = g7;
        }
      }
    }

    // scores: s = B_j - acc/512 ; top-2, ascending j (first-index ties)
#pragma unroll
    for (int js = 0; js < 4; ++js) {
      int j = jt * 64 + js * 16 + l15;
      float Bj = BsL[j];
#pragma unroll
      for (int r = 0; r < 4; ++r) {
        float s = fmaf(SCORE_SCALE, acc[js][r], Bj);
        bool lt = s < b1v[r];
        float other = lt ? b1v[r] : s;
        b2v[r] = fminf(b2v[r], other);
        b1v[r] = fminf(b1v[r], s);
        b1i[r] = lt ? j : b1i[r];
      }
    }
    __syncthreads();
  }

  // merge top-2 across the 16 lanes sharing rows
#pragma unroll
  for (int mk = 1; mk < 16; mk <<= 1) {
#pragma unroll
    for (int r = 0; r < 4; ++r) {
      float ov1 = __shfl_xor(b1v[r], mk, 64);
      float ov2 = __shfl_xor(b2v[r], mk, 64);
      int oi1 = __shfl_xor(b1i[r], mk, 64);
      bool lt = ov1 < b1v[r];
      float hi = lt ? b1v[r] : ov1;
      b2v[r] = fminf(fminf(b2v[r], ov2), hi);
      b1v[r] = fminf(b1v[r], ov1);
      b1i[r] = lt ? oi1 : b1i[r];
    }
  }
  if (l15 == 0) {
#pragma unroll
    for (int r = 0; r < 4; ++r) {
      int rr = wv * 16 + lk * 4 + r;       // D row = (lane>>4)*4 + reg
      bestj[rr] = b1i[r];
      bestd[rr] = b1v[r];
      flg[rr] = (b2v[r] - b1v[r] <= M_GAP) ? 1 : 0;
    }
  }
  __syncthreads();

  if (t < 64) {
    int n = bid * 64 + t;
    idxo[n] = (float)bestj[t];             // provisional for flagged rows
    if (flg[t]) { unsigned pos = atomicAdd(cnt, 1u); list[pos] = (unsigned)n; }
  }

  // loss for unflagged rows: dist^2 = rowA + s_best (tolerance is huge)
  {
    float lv = (t < 64 && !flg[t]) ? (rowA[t] + bestd[t]) : 0.f;
#pragma unroll
    for (int off = 32; off > 0; off >>= 1) lv += __shfl_down(lv, off, 64);
    if (lane == 0) wred[wv] = lv;
  }
  __syncthreads();
  if (t == 0)
    atomicAdd(loss, (wred[0] + wred[1] + wred[2] + wred[3]) * (1.25f / (float)NELEM));

  // zq gather (all rows; exact overwrites flagged): cb rows -> LDS -> coalesced
  f32x4* ldsF4 = reinterpret_cast<f32x4*>(buf);
  const float4* cb4 = reinterpret_cast<const float4*>(cb);
#pragma unroll
  for (int i = 0; i < 16; ++i) {
    int item = t + i * 256;            // 0..4095: rr = item>>6, cc = item&63
    int rr = item >> 6, cc = item & 63;
    float4 v = cb4[(size_t)bestj[rr] * 64 + cc];
    ldsF4[rr * 64 + (cc ^ ((rr >> 2) & 7))] = (f32x4){v.x, v.y, v.z, v.w};
  }
  __syncthreads();
  const float* ldsF = reinterpret_cast<const float*>(buf);
  float* zqb = zq + (size_t)(bid >> 6) * 1048576 + (size_t)(bid & 63) * 64;
#pragma unroll
  for (int i = 0; i < 16; ++i) {
    int item = t + i * 256;            // w4 = t&15, c = (t>>4) + 16i
    int w4 = item & 15, c = item >> 4;
    float ov[4];
#pragma unroll
    for (int q = 0; q < 4; ++q) {
      int rr = w4 * 4 + q;
      ov[q] = ldsF[(rr * 64 + ((c >> 2) ^ ((rr >> 2) & 7))) * 4 + (c & 3)];
    }
    *reinterpret_cast<float4*>(zqb + (size_t)c * 4096 + w4 * 4) =
        make_float4(ov[0], ov[1], ov[2], ov[3]);
  }
}

// ---- exact: batched np-chain rescore, 8 flagged rows per block ----
__global__ __launch_bounds__(256)
void vq_exact(const float* __restrict__ z, const float* __restrict__ cb,
              const float* __restrict__ cbT, const float* __restrict__ Bsg,
              const unsigned* __restrict__ list, const unsigned* __restrict__ cnt,
              float* __restrict__ zq, float* __restrict__ loss,
              float* __restrict__ idxo) {
  __shared__ float zr[8][260];
  __shared__ float Anp[8];
  __shared__ int jwin[8];
  __shared__ float rv[256];
  __shared__ int ri[256];
  __shared__ float lred[256];
  const int t = threadIdx.x;
  const unsigned K = *cnt;
  const float4* cbT4 = reinterpret_cast<const float4*>(cbT);

  for (unsigned g = blockIdx.x; g * 8 < K; g += gridDim.x) {
    int nrows = (int)min(8u, K - g * 8);
    __syncthreads();   // guard shared reuse across iterations
    {
      int r = t >> 5, l32 = t & 31;
      if (r < nrows) {
        int n = (int)list[g * 8 + r];
        int b = n >> 12, hw = n & 4095;
        const float* zb = z + (size_t)b * 1048576 + hw;
#pragma unroll
        for (int q = 0; q < 8; ++q) {
          int c = l32 * 8 + q;
          zr[r][c] = zb[(size_t)c * 4096];
        }
      }
    }
    __syncthreads();
    if (t < nrows) Anp[t] = np_sumsq256(&zr[t][0], 1);
    __syncthreads();

    // shared cbT read: per c one float4 (j = 4t..4t+3) feeds all 8 rows
    float acc[8][4];
#pragma unroll
    for (int r = 0; r < 8; ++r)
#pragma unroll
      for (int q = 0; q < 4; ++q) acc[r][q] = 0.f;
    for (int c = 0; c < 256; ++c) {
      float4 bv = cbT4[c * 256 + t];
#pragma unroll
      for (int r = 0; r < 8; ++r) {
        float zc = zr[r][c];
        acc[r][0] = fmaf(zc, bv.x, acc[r][0]);
        acc[r][1] = fmaf(zc, bv.y, acc[r][1]);
        acc[r][2] = fmaf(zc, bv.z, acc[r][2]);
        acc[r][3] = fmaf(zc, bv.w, acc[r][3]);
      }
    }

    // per-row argmin: d = fl(fl(A+B) - 2C), first-index ties
    for (int r = 0; r < 8; ++r) {
      if (r >= nrows) break;
      float A = Anp[r];
      float bvv = 3.4e38f;
      int bii = 0;
#pragma unroll
      for (int q = 0; q < 4; ++q) {
        int j = t * 4 + q;
        float dd = __fsub_rn(__fadd_rn(A, Bsg[j]), __fmul_rn(2.0f, acc[r][q]));
        if (dd < bvv) { bvv = dd; bii = j; }
      }
      rv[t] = bvv; ri[t] = bii;
      __syncthreads();
      for (int s2 = 128; s2 > 0; s2 >>= 1) {
        if (t < s2) {
          float v2 = rv[t + s2]; int i2 = ri[t + s2];
          if (v2 < rv[t] || (v2 == rv[t] && i2 < ri[t])) { rv[t] = v2; ri[t] = i2; }
        }
        __syncthreads();
      }
      if (t == 0) jwin[r] = ri[0];
      __syncthreads();
    }

    // outputs: idx, zq column, loss
    float lacc = 0.f;
    for (int r = 0; r < nrows; ++r) {
      int n = (int)list[g * 8 + r];
      int b = n >> 12, hw = n & 4095;
      int jw = jwin[r];
      float cv = cb[(size_t)jw * 256 + t];
      zq[(size_t)b * 1048576 + (size_t)t * 4096 + hw] = cv;
      if (t == 0) idxo[n] = (float)jw;
      float d = cv - zr[r][t];
      lacc += d * d;
    }
    lred[t] = lacc;
    __syncthreads();
    for (int s2 = 128; s2 > 0; s2 >>= 1) {
      if (t < s2) lred[t] += lred[t + s2];
      __syncthreads();
    }
    if (t == 0) atomicAdd(loss, lred[0] * (1.25f / (float)NELEM));
  }
}

// ---- fallback (round-2 validated all-exact kernel) ----
__global__ __launch_bounds__(256)
void vq_ref(const float* __restrict__ z, const float* __restrict__ cb,
            float* __restrict__ zq, float* __restrict__ loss,
            float* __restrict__ idxo) {
  __shared__ __align__(16) float zt[256 * 64];
  __shared__ __align__(16) float cbt[256 * 64];
  __shared__ float As[64];
  __shared__ float Bs[64];
  __shared__ int bestj[64];
  __shared__ float cand_v[16 * 64];
  __shared__ int cand_i[16 * 64];
  __shared__ double wred[4];
  const int t = threadIdx.x;
  const int wg = t & 15, jg = t >> 4;
  const int bid = blockIdx.x;
  const int b = bid >> 6, h = bid & 63;
  const int n0 = bid * 64;
  const float4* z4 = reinterpret_cast<const float4*>(z + (size_t)b * 256 * 4096 + (size_t)h * 64);
  float4* zt4 = reinterpret_cast<float4*>(zt);
#pragma unroll
  for (int i = 0; i < 16; ++i) {
    int idx4 = t + i * 256;
    zt4[idx4] = z4[(size_t)(idx4 >> 4) * 1024 + (idx4 & 15)];
  }
  __syncthreads();
  if (t < 64) As[t] = np_sumsq256(zt + t, 64);
  float bv[4]; int bi[4];
#pragma unroll
  for (int a = 0; a < 4; ++a) { bv[a] = 3.4e38f; bi[a] = 0; }
  for (int p = 0; p < 16; ++p) {
    __syncthreads();
    const float4* cb4 = reinterpret_cast<const float4*>(cb) + (size_t)p * 64 * 64;
#pragma unroll
    for (int i = 0; i < 16; ++i) {
      int idx4 = t + i * 256;
      int jj = idx4 >> 6, c4 = idx4 & 63;
      float4 v = cb4[idx4];
      cbt[(c4 * 4 + 0) * 64 + jj] = v.x;
      cbt[(c4 * 4 + 1) * 64 + jj] = v.y;
      cbt[(c4 * 4 + 2) * 64 + jj] = v.z;
      cbt[(c4 * 4 + 3) * 64 + jj] = v.w;
    }
    __syncthreads();
    if (t < 64) Bs[t] = np_sumsq256(cbt + t, 64);
    float acc[4][4];
#pragma unroll
    for (int a = 0; a < 4; ++a)
#pragma unroll
      for (int u = 0; u < 4; ++u) acc[a][u] = 0.0f;
    const float4* ztp = reinterpret_cast<const float4*>(zt) + wg;
    const float4* cbp = reinterpret_cast<const float4*>(cbt) + jg;
#pragma unroll 4
    for (int c = 0; c < 256; ++c) {
      float4 zv = ztp[c * 16];
      float4 cv = cbp[c * 16];
      float za[4] = {zv.x, zv.y, zv.z, zv.w};
      float ca[4] = {cv.x, cv.y, cv.z, cv.w};
#pragma unroll
      for (int a = 0; a < 4; ++a)
#pragma unroll
        for (int u = 0; u < 4; ++u) acc[a][u] = fmaf(za[a], ca[u], acc[a][u]);
    }
    __syncthreads();
#pragma unroll
    for (int u = 0; u < 4; ++u) {
      int j = p * 64 + jg * 4 + u;
      float Bju = Bs[jg * 4 + u];
#pragma unroll
      for (int a = 0; a < 4; ++a) {
        float AB = __fadd_rn(As[wg * 4 + a], Bju);
        float dd = __fsub_rn(AB, __fmul_rn(2.0f, acc[a][u]));
        if (dd < bv[a]) { bv[a] = dd; bi[a] = j; }
      }
    }
  }
  __syncthreads();
#pragma unroll
  for (int a = 0; a < 4; ++a) {
    int w = wg * 4 + a;
    cand_v[jg * 64 + w] = bv[a];
    cand_i[jg * 64 + w] = bi[a];
  }
  __syncthreads();
  if (t < 64) {
    float v0 = cand_v[t]; int i0 = cand_i[t];
    for (int g = 1; g < 16; ++g) {
      float v = cand_v[g * 64 + t]; int ii = cand_i[g * 64 + t];
      if (v < v0 || (v == v0 && ii < i0)) { v0 = v; i0 = ii; }
    }
    bestj[t] = i0;
    idxo[n0 + t] = (float)i0;
  }
  __syncthreads();
  double lsum = 0.0;
  float* zqbase = zq + (size_t)b * 256 * 4096 + (size_t)h * 64;
  for (int i = 0; i < 64; ++i) {
    int idx = t + i * 256;
    int c = idx >> 6, w = idx & 63;
    float zvv = zt[c * 64 + w];
    float cvv = cb[(size_t)bestj[w] * 256 + c];
    zqbase[(size_t)c * 4096 + w] = cvv;
    double d = (double)cvv - (double)zvv;
    lsum += d * d;
  }
#pragma unroll
  for (int off = 32; off > 0; off >>= 1) lsum += __shfl_down(lsum, off, 64);
  if ((t & 63) == 0) wred[t >> 6] = lsum;
  __syncthreads();
  if (t == 0) {
    double tot = wred[0] + wred[1] + wred[2] + wred[3];
    atomicAdd(loss, (float)(tot * (1.25 / (double)NELEM)));
  }
}

extern "C" void kernel_launch(void* const* d_in, const int* in_sizes, int n_in,
                              void* d_out, int out_size, void* d_ws, size_t ws_size,
                              hipStream_t stream) {
  (void)in_sizes; (void)n_in; (void)out_size;
  const float* z = (const float*)d_in[0];
  const float* cb = (const float*)d_in[1];
  float* out = (float*)d_out;
  float* zq = out;
  float* loss = out + NELEM;
  float* idxo = out + NELEM + 1;
  if (ws_size < 1712128) {   // scratch too small: validated all-exact path
    hipMemsetAsync(loss, 0, sizeof(float), stream);
    vq_ref<<<512, 256, 0, stream>>>(z, cb, zq, loss, idxo);
    return;
  }
  unsigned char* ws = (unsigned char*)d_ws;
  unsigned* cnt = (unsigned*)ws;                             // 4 B
  float* Bsg = (float*)(ws + 1024);                          // 4 KB
  unsigned* list = (unsigned*)(ws + 8192);                   // 128 KB
  float* cbT = (float*)(ws + 139264);                        // 1 MB
  unsigned short* cbimg = (unsigned short*)(ws + 1187840);   // 512 KB fp16
  vq_prep<<<16, 256, 0, stream>>>(cb, cbimg, cbT, Bsg, cnt, loss);
  vq_fast<<<512, 256, 0, stream>>>(z, cb, cbimg, Bsg, zq, loss, idxo, list, cnt);
  vq_exact<<<512, 256, 0, stream>>>(z, cb, cbT, Bsg, list, cnt, zq, loss, idxo);
}